// Round 11
// baseline (99.214 us; speedup 1.0000x reference)
//
#include <hip/hip_runtime.h>

// Attention 8192x8192, D=DV=64, fp32 in/out.
// R11: halve the per-CU memory term. Waves remapped to 2 row-halves x 4
// key-chunks (rt=2): wave w and w+4 load identical K/V fragments -> L1 hits /
// MSHR merge (0.5 MB effective fill per CU, was 1 MB). Depth-3 prefetch
// (unroll-6, fixed parity) covers the ~500cy L3 latency at the halved chunk
// time. Two-stage QKEXP(t)||PV(t-1) pipeline, truncation P pack, fixed-offset
// softmax, fragment-linear bf16 K/Vt prepass, (O,l) partials + merge kernel.

#define NQ 8192
#define NK 8192

typedef float f32x4 __attribute__((ext_vector_type(4)));
typedef short short8 __attribute__((ext_vector_type(8)));
union U4 { uint4 u; short8 s; };

#define MFMA16 __builtin_amdgcn_mfma_f32_16x16x32_bf16

// round-to-nearest-even fp32->bf16 pair pack (lo = a) — prepass/Q only
__device__ __forceinline__ unsigned pk2(float a, float b) {
    unsigned ua = __builtin_bit_cast(unsigned, a);
    unsigned ub = __builtin_bit_cast(unsigned, b);
    ua = (ua + 0x7FFFu + ((ua >> 16) & 1u)) >> 16;
    ub = (ub + 0x7FFFu + ((ub >> 16) & 1u)) & 0xFFFF0000u;
    return ua | ub;
}

// 1-op truncation pack: dst = {hi16(b), hi16(a)} (lo = a)
__device__ __forceinline__ unsigned pkt(float a, float b) {
    return __builtin_amdgcn_perm(__builtin_bit_cast(unsigned, b),
                                 __builtin_bit_cast(unsigned, a), 0x07060302u);
}

// ---- prepass: swizzle K/V into fragment-linear bf16 layouts ----
__global__ __launch_bounds__(256)
void prepass(const float* __restrict__ Kg, const float* __restrict__ Vg,
             uint4* __restrict__ Kb4, uint4* __restrict__ Vt4) {
    __shared__ float ld[64 * 33];
    const int t = threadIdx.x, b = blockIdx.x;

    if (b < 256) {
        const int kl = t >> 3, dg = t & 7;
        const int e = kl & 1, i16 = kl >> 1, h = dg >> 2, q = dg & 3;
        const float* gp = Kg + (size_t)(b * 32 + kl) * 64 + dg * 8;
        float4 f0 = *(const float4*)gp;
        float4 f1 = *(const float4*)(gp + 4);
        uint4 o = make_uint4(pk2(f0.x, f0.y), pk2(f0.z, f0.w),
                             pk2(f1.x, f1.y), pk2(f1.z, f1.w));
        Kb4[(size_t)(b * 4 + e * 2 + h) * 64 + i16 * 4 + q] = o;
    } else {
        const int c = b - 256;
        {
            const int key = t >> 3, dg = t & 7;
            const float* gp = Vg + (size_t)(c * 32 + key) * 64 + dg * 8;
            float4 f0 = *(const float4*)gp;
            float4 f1 = *(const float4*)(gp + 4);
            ld[(dg * 8 + 0) * 33 + key] = f0.x;
            ld[(dg * 8 + 1) * 33 + key] = f0.y;
            ld[(dg * 8 + 2) * 33 + key] = f0.z;
            ld[(dg * 8 + 3) * 33 + key] = f0.w;
            ld[(dg * 8 + 4) * 33 + key] = f1.x;
            ld[(dg * 8 + 5) * 33 + key] = f1.y;
            ld[(dg * 8 + 6) * 33 + key] = f1.z;
            ld[(dg * 8 + 7) * 33 + key] = f1.w;
        }
        __syncthreads();
        {
            const int dim = t >> 2, kq = t & 3;
            const int dt = dim >> 4, i16 = dim & 15;
            float v[8];
            #pragma unroll
            for (int j = 0; j < 8; ++j) v[j] = ld[dim * 33 + kq * 8 + j];
            uint4 o = make_uint4(pk2(v[0], v[1]), pk2(v[2], v[3]),
                                 pk2(v[4], v[5]), pk2(v[6], v[7]));
            Vt4[(size_t)(c * 4 + dt) * 64 + i16 * 4 + kq] = o;
        }
    }
}

// ---- main kernel: 64 rows x 4096 keys per block, writes (O,l) partials ----
__global__ __launch_bounds__(512, 1)
void attn_main(const float* __restrict__ Qg,
               const uint4* __restrict__ Kb4,
               const uint4* __restrict__ Vt4,
               float* __restrict__ Opart,
               float* __restrict__ Lpart) {
    // LDS: P regions [w 0..7][rt 0..1][par 0..1] x 64 uint4 = 2048 uint4 (32KB)
    // during the loop; 8 merge regions x 2080 floats (66,560 B) after.
    __shared__ uint4 shb4[4160];
    float* sF = (float*)shb4;
    unsigned* shu = (unsigned*)shb4;

    const int t = threadIdx.x, w = t >> 6, lane = t & 63;
    const int q = lane >> 4, i16 = lane & 15;
    const int rw = w >> 2;           // row-half 0/1
    const int kc = w & 3;            // key-chunk within tile
    const int bid = blockIdx.x;
    const int kh = bid & 1;          // key half 0/1
    const int rg = bid >> 1;         // row group 0..127
    const int qb0 = rg * 64;
    const int lsl = i16 * 4 + q;     // lane-linear slot (0..63)
    const int phase = rg & 31;       // tile-order rotation (32 tiles of 128 keys)

    // Q fragments: 2 row-tiles for this wave's row-half (scale 1/8*log2e folded)
    const float SCL = 0.18033688011112042f;
    short8 aq[2][2];
    #pragma unroll
    for (int rt = 0; rt < 2; ++rt) {
        const float* qp = Qg + (size_t)(qb0 + rw * 32 + rt * 16 + i16) * 64 + q * 8;
        float4 f0 = *(const float4*)(qp);
        float4 f1 = *(const float4*)(qp + 4);
        U4 u;
        u.u = make_uint4(pk2(f0.x * SCL, f0.y * SCL), pk2(f0.z * SCL, f0.w * SCL),
                         pk2(f1.x * SCL, f1.y * SCL), pk2(f1.z * SCL, f1.w * SCL));
        aq[rt][0] = u.s;
        f0 = *(const float4*)(qp + 32);
        f1 = *(const float4*)(qp + 36);
        u.u = make_uint4(pk2(f0.x * SCL, f0.y * SCL), pk2(f0.z * SCL, f0.w * SCL),
                         pk2(f1.x * SCL, f1.y * SCL), pk2(f1.z * SCL, f1.w * SCL));
        aq[rt][1] = u.s;
    }

    f32x4 acc[2][4];           // O partial accumulators, static idx
    float lsum[2][4];          // per-lane row-sum partials (VALU)
    #pragma unroll
    for (int rt = 0; rt < 2; ++rt) {
        #pragma unroll
        for (int dt = 0; dt < 4; ++dt) { acc[rt][dt][0]=0.f; acc[rt][dt][1]=0.f; acc[rt][dt][2]=0.f; acc[rt][dt][3]=0.f; }
        #pragma unroll
        for (int r = 0; r < 4; ++r) lsum[rt][r] = 0.f;
    }

    // P slot indices (layout verified in R2-R10)
    const int tpw = ((i16 >> 2) & 1) + 2 * q + 32 * (i16 >> 3);  // tp = tpw + 8r
    const int pp  = i16 & 3;
    const int tpr = (q & 1) + 2 * ((i16 >> 2) & 3) + 8 * (i16 & 3) + 32 * (q >> 1);

    uint4 kfA[4], vfA[4], kfB[4], vfB[4], kfC[4], vfC[4];

    // chunk base: tile TT (128 keys) -> chunk = T*4 + kc within key-half kh
#define LOAD_T(TT, KD, VD)                                                           \
    do {                                                                             \
        const int cb = ((kh << 7) + ((((TT) + phase) & 31) * 4 + kc)) * 4;           \
        _Pragma("unroll")                                                            \
        for (int eh = 0; eh < 4; ++eh)                                               \
            (KD)[eh] = Kb4[(size_t)(cb + eh) * 64 + lsl];                            \
        _Pragma("unroll")                                                            \
        for (int dt = 0; dt < 4; ++dt)                                               \
            (VD)[dt] = Vt4[(size_t)(cb + dt) * 64 + lsl];                            \
    } while (0)

    // stage 1: QK^T -> exp2 -> truncation-pack P into parity region PAR
#define QKEXP(KD, PAR)                                                               \
    do {                                                                             \
        _Pragma("unroll")                                                            \
        for (int rt = 0; rt < 2; ++rt) {                                             \
            f32x4 s0, s1;                                                            \
            s0[0]=-16.f; s0[1]=-16.f; s0[2]=-16.f; s0[3]=-16.f;                      \
            s1[0]=-16.f; s1[1]=-16.f; s1[2]=-16.f; s1[3]=-16.f;                      \
            U4 u0, u1, u2, u3;                                                       \
            u0.u = (KD)[0]; u1.u = (KD)[1]; u2.u = (KD)[2]; u3.u = (KD)[3];          \
            s0 = MFMA16(aq[rt][0], u0.s, s0, 0, 0, 0);                               \
            s0 = MFMA16(aq[rt][1], u1.s, s0, 0, 0, 0);                               \
            s1 = MFMA16(aq[rt][0], u2.s, s1, 0, 0, 0);                               \
            s1 = MFMA16(aq[rt][1], u3.s, s1, 0, 0, 0);                               \
            const int rbase = (((w * 2 + rt) * 2) + (PAR)) * 256;                    \
            _Pragma("unroll")                                                        \
            for (int r = 0; r < 4; ++r) {                                            \
                float p0 = __builtin_amdgcn_exp2f(s0[r]);                            \
                float p1 = __builtin_amdgcn_exp2f(s1[r]);                            \
                lsum[rt][r] += p0;                                                   \
                lsum[rt][r] += p1;                                                   \
                shu[rbase + (tpw + 8 * r) * 4 + pp] = pkt(p0, p1);                   \
            }                                                                        \
        }                                                                            \
    } while (0)

    // stage 2: read P A-frags from parity region PAR, PV MFMA
#define PVS(VD, PAR)                                                                 \
    do {                                                                             \
        U4 ap[2];                                                                    \
        _Pragma("unroll")                                                            \
        for (int rt = 0; rt < 2; ++rt)                                               \
            ap[rt].u = shb4[(((w * 2 + rt) * 2) + (PAR)) * 64 + tpr];                \
        _Pragma("unroll")                                                            \
        for (int dt = 0; dt < 4; ++dt) {                                             \
            U4 bv; bv.u = (VD)[dt];                                                  \
            _Pragma("unroll")                                                        \
            for (int rt = 0; rt < 2; ++rt)                                           \
                acc[rt][dt] = MFMA16(ap[rt].s, bv.s, acc[rt][dt], 0, 0, 0);          \
        }                                                                            \
    } while (0)

    // ---- depth-3, unroll-6 pipelined loop: QKEXP(t) || PV(t-1) ----
    LOAD_T(0, kfA, vfA);
    LOAD_T(1, kfB, vfB);
    LOAD_T(2, kfC, vfC);
    __builtin_amdgcn_sched_barrier(0);
    QKEXP(kfA, 0);                        // tile 0
    #pragma unroll 1
    for (int tt = 1; tt < 31; tt += 6) {
        QKEXP(kfB, 1); PVS(vfA, 0); LOAD_T(tt + 2, kfA, vfA);
        __builtin_amdgcn_sched_barrier(0);
        QKEXP(kfC, 0); PVS(vfB, 1); LOAD_T(tt + 3, kfB, vfB);
        __builtin_amdgcn_sched_barrier(0);
        QKEXP(kfA, 1); PVS(vfC, 0); LOAD_T(tt + 4, kfC, vfC);
        __builtin_amdgcn_sched_barrier(0);
        QKEXP(kfB, 0); PVS(vfA, 1); LOAD_T(tt + 5, kfA, vfA);
        __builtin_amdgcn_sched_barrier(0);
        QKEXP(kfC, 1); PVS(vfB, 0); LOAD_T(tt + 6, kfB, vfB);
        __builtin_amdgcn_sched_barrier(0);
        QKEXP(kfA, 0); PVS(vfC, 1); LOAD_T(tt + 7, kfC, vfC);
        __builtin_amdgcn_sched_barrier(0);
    }
    QKEXP(kfB, 1);                        // tile 31
    PVS(vfA, 0);                          // PV(30)
    PVS(vfB, 1);                          // PV(31)

    // ---- reduce row-sum partials across the 16 key-lanes of each quad ----
    #pragma unroll
    for (int rt = 0; rt < 2; ++rt)
        #pragma unroll
        for (int r = 0; r < 4; ++r) {
            float v = lsum[rt][r];
            v += __shfl_xor(v, 1);
            v += __shfl_xor(v, 2);
            v += __shfl_xor(v, 4);
            v += __shfl_xor(v, 8);
            lsum[rt][r] = v;   // uniform across the 16 lanes of quad q
        }

    // ---- tree-merge the 4 key-chunk partials within each row-half ----
    __syncthreads();
    for (int step = 2; step >= 1; step >>= 1) {
        if (kc >= step && kc < 2 * step) {
            float* base = sF + (w - step) * 2080;
            #pragma unroll
            for (int rt = 0; rt < 2; ++rt) {
                #pragma unroll
                for (int dt = 0; dt < 4; ++dt)
                    #pragma unroll
                    for (int r = 0; r < 4; ++r)
                        base[(rt * 16 + 4 * q + r) * 64 + dt * 16 + i16] = acc[rt][dt][r];
                if (i16 == 0) {
                    #pragma unroll
                    for (int r = 0; r < 4; ++r) base[2048 + rt * 16 + 4 * q + r] = lsum[rt][r];
                }
            }
        }
        __syncthreads();
        if (kc < step) {
            const float* base = sF + w * 2080;
            #pragma unroll
            for (int rt = 0; rt < 2; ++rt) {
                #pragma unroll
                for (int dt = 0; dt < 4; ++dt)
                    #pragma unroll
                    for (int r = 0; r < 4; ++r)
                        acc[rt][dt][r] += base[(rt * 16 + 4 * q + r) * 64 + dt * 16 + i16];
                #pragma unroll
                for (int r = 0; r < 4; ++r) lsum[rt][r] += base[2048 + rt * 16 + 4 * q + r];
            }
        }
        __syncthreads();
    }

    // ---- waves 0 and 4 write their row-half's (O,l) partial to global ----
    if (kc == 0) {
        #pragma unroll
        for (int rt = 0; rt < 2; ++rt) {
            #pragma unroll
            for (int dt = 0; dt < 4; ++dt)
                #pragma unroll
                for (int r = 0; r < 4; ++r) {
                    const int row = qb0 + rw * 32 + rt * 16 + 4 * q + r;
                    Opart[((size_t)kh * 8192 + row) * 64 + dt * 16 + i16] = acc[rt][dt][r];
                }
            if (i16 == 0) {
                #pragma unroll
                for (int r = 0; r < 4; ++r)
                    Lpart[kh * 8192 + qb0 + rw * 32 + rt * 16 + 4 * q + r] = lsum[rt][r];
            }
        }
    }
}

// ---- merge: O = (O0 + O1) / (l0 + l1) ----
__global__ __launch_bounds__(256)
void merge(const float* __restrict__ Opart, const float* __restrict__ Lpart,
           float* __restrict__ Og) {
    const int idx = blockIdx.x * 256 + threadIdx.x;   // 0..131071
    const int row = idx >> 4, seg = idx & 15;
    const float4 a = *(const float4*)(Opart + (size_t)row * 64 + seg * 4);
    const float4 b = *(const float4*)(Opart + ((size_t)8192 + row) * 64 + seg * 4);
    const float inv = 1.0f / (Lpart[row] + Lpart[8192 + row]);
    float4 o;
    o.x = (a.x + b.x) * inv;
    o.y = (a.y + b.y) * inv;
    o.z = (a.z + b.z) * inv;
    o.w = (a.w + b.w) * inv;
    *(float4*)(Og + (size_t)row * 64 + seg * 4) = o;
}

extern "C" void kernel_launch(void* const* d_in, const int* in_sizes, int n_in,
                              void* d_out, int out_size, void* d_ws, size_t ws_size,
                              hipStream_t stream) {
    const float* Q = (const float*)d_in[0];
    const float* K = (const float*)d_in[1];
    const float* V = (const float*)d_in[2];
    float* O = (float*)d_out;
    char* ws = (char*)d_ws;
    uint4* Kb4   = (uint4*)ws;                        // 1 MB, fragment-linear
    uint4* Vt4   = (uint4*)(ws + (1 << 20));          // 1 MB, fragment-linear
    float* Opart = (float*)(ws + (2 << 20));          // 2 x 8192 x 64 fp32 = 4 MB
    float* Lpart = (float*)(ws + (6 << 20));          // 2 x 8192 fp32
    hipLaunchKernelGGL(prepass, dim3(512), dim3(256), 0, stream, K, V, Kb4, Vt4);
    hipLaunchKernelGGL(attn_main, dim3(256), dim3(512), 0, stream, Q, Kb4, Vt4, Opart, Lpart);
    hipLaunchKernelGGL(merge, dim3(512), dim3(256), 0, stream, Opart, Lpart, O);
}